// Round 4
// baseline (746.930 us; speedup 1.0000x reference)
//
#include <hip/hip_runtime.h>

#define NB 8
#define NP 1024
#define NR 8192

typedef unsigned short u16;
typedef __attribute__((ext_vector_type(8))) short bf16x8;   // 8 bf16 (4 VGPRs)
typedef __attribute__((ext_vector_type(4))) float f32x4;
typedef __attribute__((ext_vector_type(4))) unsigned int u32x4;

#define MFMA __builtin_amdgcn_mfma_f32_16x16x32_bf16

static __device__ __forceinline__ float bf2f(u16 u) {
    union { unsigned int i; float f; } v; v.i = ((unsigned int)u) << 16; return v.f;
}
static __device__ __forceinline__ unsigned int f2bf(float f) {
    union { float fv; unsigned int i; } v; v.fv = f;
    unsigned int r = v.i + 0x7FFFu + ((v.i >> 16) & 1u);   // RNE
    return r >> 16;
}
static __device__ __forceinline__ unsigned int pack2(float a, float b) {
    return f2bf(a) | (f2bf(b) << 16);
}
static __device__ __forceinline__ void unpk8(uint4 v, float* o) {
    o[0] = bf2f((u16)(v.x & 0xFFFF)); o[1] = bf2f((u16)(v.x >> 16));
    o[2] = bf2f((u16)(v.y & 0xFFFF)); o[3] = bf2f((u16)(v.y >> 16));
    o[4] = bf2f((u16)(v.z & 0xFFFF)); o[5] = bf2f((u16)(v.z >> 16));
    o[6] = bf2f((u16)(v.w & 0xFFFF)); o[7] = bf2f((u16)(v.w >> 16));
}

struct CoopArgs {
    const u32x4* Rr4; const u32x4* Rs4;
    u16* recv; u16* send;
    const float* state; const float* Ra;
    const float* re_w0; const float* re_w1; const float* re_w2;
    const float* rp_w;  const float* pp_w;  const float* pr_w0;
    const float* pe_w0; const float* pe_w1;
    bf16x8* wfrag;
    const float* pe_b0; const float* pe_b1;
    const float* re_b0; const float* re_b1; const float* re_b2;
    const float* rp_b;  const float* pp_b;  const float* pr_b0;
    const float* pr_w1; const float* pr_b1;
    u16* penc; u16* bufP; u16* UVa; u16* UVb;
    float* peff32; float* out;
    int* row_ptr; unsigned int* pidx;
    int* bar;                      // 4 one-shot grid-barrier counters (memset to 0)
};

// ---- manual grid barrier (plain launch, graph-capture safe) ----
// All 256 blocks are guaranteed co-resident: LDS 21.5KB -> 7 blocks/CU,
// VGPR worst case 2 blocks/CU -> capacity >= 512 >= grid. No deadlock.
// __threadfence() emits agent-scope L2 writeback/invalidate -> cross-XCD visibility.
static __device__ __forceinline__ void gbar(int* cnt, int tid) {
    __syncthreads();
    if (tid == 0) {
        __threadfence();                               // release
        atomicAdd(cnt, 1);
        while (__hip_atomic_load(cnt, __ATOMIC_RELAXED, __HIP_MEMORY_SCOPE_AGENT) < 256)
            __builtin_amdgcn_s_sleep(8);
        __threadfence();                               // acquire
    }
    __syncthreads();
}

// ---------------- MFMA tile core ----------------
template<int KC>
static __device__ __forceinline__ void load_wfrag(
    const bf16x8* __restrict__ fb, bf16x8 (&wf)[KC][2], int tid)
{
    #pragma unroll
    for (int kc = 0; kc < KC; ++kc)
      #pragma unroll
      for (int nt = 0; nt < 2; ++nt)
        wf[kc][nt] = fb[(kc*2 + nt)*256 + tid];
}

template<int MT, int KC, int LDA>
static __device__ __forceinline__ void mfma_compute(
    const u16* xlds, const bf16x8 (&wf)[KC][2], f32x4 (&acc)[MT][2],
    int l16, int quad)
{
    #pragma unroll
    for (int kc = 0; kc < KC; ++kc) {
        bf16x8 a[MT];
        #pragma unroll
        for (int mt = 0; mt < MT; ++mt)
            a[mt] = *(const bf16x8*)(xlds + (mt*16 + l16)*LDA + kc*32 + quad*8);
        #pragma unroll
        for (int mt = 0; mt < MT; ++mt) {
            acc[mt][0] = MFMA(a[mt], wf[kc][0], acc[mt][0], 0, 0, 0);
            acc[mt][1] = MFMA(a[mt], wf[kc][1], acc[mt][1], 0, 0, 0);
        }
    }
}

template<int MT>
static __device__ __forceinline__ void zero_acc(f32x4 (&acc)[MT][2]) {
    #pragma unroll
    for (int mt = 0; mt < MT; ++mt)
      #pragma unroll
      for (int nt = 0; nt < 2; ++nt)
        acc[mt][nt] = f32x4{0.f, 0.f, 0.f, 0.f};
}

template<int MT, int LDA>
static __device__ __forceinline__ void store_c_lds(
    u16* xlds, const f32x4 (&acc)[MT][2], const float* __restrict__ bias,
    int wave, int quad, int l16, int coloff = 0)
{
    #pragma unroll
    for (int mt = 0; mt < MT; ++mt)
      #pragma unroll
      for (int nt = 0; nt < 2; ++nt) {
        int col = wave*32 + nt*16 + l16;
        float bv = bias[col];
        #pragma unroll
        for (int rg = 0; rg < 4; ++rg)
            xlds[(mt*16 + quad*4 + rg)*LDA + coloff + col] =
                (u16)f2bf(fmaxf(acc[mt][nt][rg] + bv, 0.f));
      }
}

template<int MT, bool RELU>
static __device__ __forceinline__ void store_c_glob(
    u16* __restrict__ out, long row0, const f32x4 (&acc)[MT][2],
    const float* __restrict__ bias, int wave, int quad, int l16)
{
    #pragma unroll
    for (int mt = 0; mt < MT; ++mt)
      #pragma unroll
      for (int nt = 0; nt < 2; ++nt) {
        int col = wave*32 + nt*16 + l16;
        float bv = bias[col];
        #pragma unroll
        for (int rg = 0; rg < 4; ++rg) {
            long r = row0 + mt*16 + quad*4 + rg;
            float v = acc[mt][nt][rg] + bv;
            if (RELU) v = fmaxf(v, 0.f);
            out[r*128 + col] = (u16)f2bf(v);
        }
      }
}

// ---------------- phase 0 helpers ----------------
static __device__ void wprep(const CoopArgs& A, int tid, int bid) {
    const float* W; int KC, kv, off;
    switch (bid) {
        case 0:  W = A.re_w0; KC = 3;  kv = 65;  off = 0;  break;  // re_w0 (pad 65->96)
        case 1:  W = A.re_w1; KC = 4;  kv = 128; off = 6;  break;
        case 2:  W = A.re_w2; KC = 4;  kv = 128; off = 14; break;
        case 3:  W = A.rp_w;  KC = 12; kv = 384; off = 32; break;  // rp: P|U|V frags
        case 4:  W = A.pp_w;  KC = 8;  kv = 256; off = 56; break;
        default: W = A.pr_w0; KC = 4;  kv = 128; off = 72; break;
    }
    int wave = tid >> 6, quad = (tid >> 4) & 3, l16 = tid & 15;
    for (int kc = 0; kc < KC; ++kc)
      for (int nt = 0; nt < 2; ++nt) {
        bf16x8 f;
        #pragma unroll
        for (int j = 0; j < 8; ++j) {
            int k = kc*32 + quad*8 + j;
            f[j] = (k < kv) ? (short)f2bf(W[k*128 + wave*32 + nt*16 + l16]) : (short)0;
        }
        A.wfrag[(off + kc*2 + nt)*256 + tid] = f;
      }
}

static __device__ void pe_tile(const CoopArgs& A, u16* xlds, int tid, int tile) {
    constexpr int LDA = 136;
    const int wave = tid >> 6, quad = (tid >> 4) & 3, l16 = tid & 15;
    const long row0 = (long)tile * 64;
    for (int idx = tid; idx < 64 * 8; idx += 256) {    // stage state fp32->bf16
        int r = idx >> 3, c = idx & 7;
        float4 v = *(const float4*)(A.state + (row0 + r)*32 + c*4);
        uint2 o; o.x = pack2(v.x, v.y); o.y = pack2(v.z, v.w);
        *(uint2*)(xlds + r*LDA + c*4) = o;
    }
    __syncthreads();
    f32x4 acc[4][2];
    zero_acc<4>(acc);
    {   // pe_w0 frags built directly (32x128, KC=1)
        bf16x8 wf[1][2];
        #pragma unroll
        for (int nt = 0; nt < 2; ++nt)
          #pragma unroll
          for (int j = 0; j < 8; ++j) {
            int k = quad*8 + j;
            wf[0][nt][j] = (short)f2bf(A.pe_w0[k*128 + wave*32 + nt*16 + l16]);
          }
        mfma_compute<4, 1, LDA>(xlds, wf, acc, l16, quad);
    }
    __syncthreads();
    store_c_lds<4, LDA>(xlds, acc, A.pe_b0, wave, quad, l16);
    __syncthreads();
    zero_acc<4>(acc);
    {   // pe_w1 frags built directly (128x128, KC=4)
        bf16x8 wf[4][2];
        #pragma unroll
        for (int kc = 0; kc < 4; ++kc)
          #pragma unroll
          for (int nt = 0; nt < 2; ++nt)
            #pragma unroll
            for (int j = 0; j < 8; ++j) {
                int k = kc*32 + quad*8 + j;
                wf[kc][nt][j] = (short)f2bf(A.pe_w1[k*128 + wave*32 + nt*16 + l16]);
            }
        mfma_compute<4, 4, LDA>(xlds, wf, acc, l16, quad);
    }
    store_c_glob<4, true>(A.penc, row0, acc, A.pe_b1, wave, quad, l16);
}

// ---------------- phase 1 helpers ----------------
static __device__ void csr_build(const CoopArgs& A, int* cur, int* wsum, int tid, int b) {
    for (int i = tid; i < NP; i += 256) cur[i] = 0;
    __syncthreads();
    int pv[32];
    #pragma unroll
    for (int k = 0; k < 32; ++k) {
        pv[k] = A.recv[b * NR + k * 256 + tid] & 1023;
        atomicAdd(&cur[pv[k]], 1);
    }
    __syncthreads();
    int4 c4v = ((const int4*)cur)[tid];    // bins 4t..4t+3
    int s = c4v.x + c4v.y + c4v.z + c4v.w;
    int si = s;                            // inclusive wave scan over thread sums
    #pragma unroll
    for (int off = 1; off < 64; off <<= 1) {
        int u = __shfl_up(si, off);
        if ((tid & 63) >= off) si += u;
    }
    if ((tid & 63) == 63) wsum[tid >> 6] = si;
    __syncthreads();
    if (tid == 0) {
        int a0 = 0;
        #pragma unroll
        for (int i = 0; i < 4; ++i) { int w = wsum[i]; wsum[i] = a0; a0 += w; }
    }
    __syncthreads();
    int base = si - s + wsum[tid >> 6];    // exclusive prefix of thread chunk
    int e0 = base, e1 = base + c4v.x, e2 = e1 + c4v.y, e3 = e2 + c4v.z;
    int* rp = A.row_ptr + b * (NP + 1);
    rp[tid*4 + 0] = e0; rp[tid*4 + 1] = e1;
    rp[tid*4 + 2] = e2; rp[tid*4 + 3] = e3;
    cur[tid*4 + 0] = e0; cur[tid*4 + 1] = e1;
    cur[tid*4 + 2] = e2; cur[tid*4 + 3] = e3;
    if (tid == 255) rp[NP] = e3 + c4v.w;
    __syncthreads();
    #pragma unroll
    for (int k = 0; k < 32; ++k) {
        int r = k * 256 + tid;
        int j = atomicAdd(&cur[pv[k]], 1) & 8191;
        A.pidx[b * NR + j] = (unsigned int)(r & 8191)
                           | ((unsigned int)(A.send[b * NR + r] & 1023) << 16);
    }
}

static __device__ void enc_tile(const CoopArgs& A, u16* xlds, int tid, int t) {
    constexpr int LDA = 136;
    const int wave = tid >> 6, quad = (tid >> 4) & 3, l16 = tid & 15;
    f32x4 acc[4][2];
    const int row0 = t * 64;
    const int b = row0 >> 13;
    {   // stage gathered input: [state_recv(32) | state_send(32) | Ra(1) | zeros->96]
        int r = tid >> 2, tt = tid & 3;
        int rel = row0 + r;
        u16* dst = xlds + r * LDA;
        int ri = A.recv[rel] & 1023;
        int si = A.send[rel] & 1023;
        const float* rrow = A.state + ((long)(b*NP + ri)) * 32;
        const float* srow = A.state + ((long)(b*NP + si)) * 32;
        float4 a0 = *(const float4*)(rrow + tt*8);
        float4 a1 = *(const float4*)(rrow + tt*8 + 4);
        uint4 o;
        o.x = pack2(a0.x, a0.y); o.y = pack2(a0.z, a0.w);
        o.z = pack2(a1.x, a1.y); o.w = pack2(a1.z, a1.w);
        *(uint4*)(dst + tt*8) = o;
        float4 s0 = *(const float4*)(srow + tt*8);
        float4 s1 = *(const float4*)(srow + tt*8 + 4);
        o.x = pack2(s0.x, s0.y); o.y = pack2(s0.z, s0.w);
        o.z = pack2(s1.x, s1.y); o.w = pack2(s1.z, s1.w);
        *(uint4*)(dst + 32 + tt*8) = o;
        if (tt == 3) {
            uint4 z = make_uint4(0, 0, 0, 0);
            *(uint4*)(dst + 64) = z; *(uint4*)(dst + 72) = z;
            *(uint4*)(dst + 80) = z; *(uint4*)(dst + 88) = z;
            dst[64] = (u16)f2bf(A.Ra[rel]);
        }
    }
    __syncthreads();
    zero_acc<4>(acc);
    {
        bf16x8 wf[3][2];
        load_wfrag<3>(A.wfrag + 0*256, wf, tid);
        mfma_compute<4, 3, LDA>(xlds, wf, acc, l16, quad);
    }
    __syncthreads();
    store_c_lds<4, LDA>(xlds, acc, A.re_b0, wave, quad, l16);
    __syncthreads();
    zero_acc<4>(acc);
    {
        bf16x8 wf[4][2];
        load_wfrag<4>(A.wfrag + 6*256, wf, tid);
        mfma_compute<4, 4, LDA>(xlds, wf, acc, l16, quad);
    }
    __syncthreads();
    store_c_lds<4, LDA>(xlds, acc, A.re_b1, wave, quad, l16);
    __syncthreads();
    zero_acc<4>(acc);
    {
        bf16x8 wf[4][2];
        load_wfrag<4>(A.wfrag + 14*256, wf, tid);
        mfma_compute<4, 4, LDA>(xlds, wf, acc, l16, quad);
    }
    __syncthreads();
    store_c_lds<4, LDA>(xlds, acc, A.re_b2, wave, quad, l16);   // relation_encode
    __syncthreads();
    zero_acc<4>(acc);
    {
        bf16x8 wf[4][2];
        load_wfrag<4>(A.wfrag + 32*256, wf, tid);
        mfma_compute<4, 4, LDA>(xlds, wf, acc, l16, quad);
    }
    __syncthreads();                                  // xlds reused by next tile
    // P (pre-relu) stored UNSORTED at bufP[rel] -> contiguous coalesced stores
    #pragma unroll
    for (int mt = 0; mt < 4; ++mt)
      #pragma unroll
      for (int nt = 0; nt < 2; ++nt) {
        int col = wave*32 + nt*16 + l16;
        float bv = A.rp_b[col];
        #pragma unroll
        for (int rg = 0; rg < 4; ++rg) {
            int rl = mt*16 + quad*4 + rg;
            A.bufP[((long)(row0 + rl))*128 + col] = (u16)f2bf(acc[mt][nt][rg] + bv);
        }
      }
}

// ---------------- pp step ----------------
template<bool STEP1, bool MAKEUV, bool LAST>
static __device__ void pp_step(const CoopArgs& A, u16* xlds, int tid, int bid,
                               const u16* UV_in, u16* UV_out)
{
    constexpr int LDA = 264;                   // 256 + 8
    const int wave = tid >> 6, quad = (tid >> 4) & 3, l16 = tid & 15;
    const long row0 = (long)bid * 32;

    for (int idx = tid; idx < 512; idx += 256) {           // seg0: particle_encode (bf16)
        int r = idx >> 4, c = idx & 15;
        *(uint4*)(xlds + r*LDA + c*8) = *(const uint4*)(A.penc + (row0 + r)*128 + c*8);
    }
    {   // seg1: agg; 8 threads/particle, 16 cols each
        int pp = tid >> 3;
        int cq = tid & 7;
        int gp = (int)row0 + pp;
        int b = gp >> 10, pl = gp & 1023;
        const int* rp = A.row_ptr + b * (NP + 1);
        int s0 = rp[pl], e0 = rp[pl + 1];
        const unsigned int* pidxb = A.pidx + b * NR;
        const u16* bufPb = A.bufP + (long)b * NR * 128;
        float a[16];
        #pragma unroll
        for (int t = 0; t < 16; ++t) a[t] = 0.f;
        float uv[16];
        if (!STEP1) {
            const u16* ur = UV_in + ((long)gp)*256 + cq*16;
            unpk8(*(const uint4*)ur, uv);
            unpk8(*(const uint4*)(ur + 8), uv + 8);
        }
        const u16* uvb = UV_in + ((long)(b*NP))*256 + 128 + cq*16;
        for (int jb = s0; jb < e0; jb += 4) {
            int m = e0 - jb; if (m > 4) m = 4;
            unsigned int ids[4];
            #pragma unroll
            for (int t = 0; t < 4; ++t) {
                int j = jb + t; if (j > e0 - 1) j = e0 - 1;   // clamp (loads stay valid)
                ids[t] = pidxb[j];
            }
            uint4 P0[4], P1[4], V0[4], V1[4];
            #pragma unroll
            for (int t = 0; t < 4; ++t) {
                const u16* prow = bufPb + ((long)(ids[t] & 8191u))*128 + cq*16;
                P0[t] = *(const uint4*)prow;
                P1[t] = *(const uint4*)(prow + 8);
                if (!STEP1) {
                    const u16* vrow = uvb + (long)((ids[t] >> 16) & 1023u)*256;
                    V0[t] = *(const uint4*)vrow;
                    V1[t] = *(const uint4*)(vrow + 8);
                }
            }
            #pragma unroll
            for (int t = 0; t < 4; ++t) {
                if (t < m) {
                    float pv[16];
                    unpk8(P0[t], pv); unpk8(P1[t], pv + 8);
                    if (STEP1) {
                        #pragma unroll
                        for (int e = 0; e < 16; ++e) a[e] += fmaxf(pv[e], 0.f);
                    } else {
                        float vv[16];
                        unpk8(V0[t], vv); unpk8(V1[t], vv + 8);
                        #pragma unroll
                        for (int e = 0; e < 16; ++e)
                            a[e] += fmaxf(pv[e] + uv[e] + vv[e], 0.f);
                    }
                }
            }
        }
        u16* dst = xlds + pp*LDA + 128 + cq*16;
        uint4 o;
        o.x = pack2(a[0], a[1]);   o.y = pack2(a[2], a[3]);
        o.z = pack2(a[4], a[5]);   o.w = pack2(a[6], a[7]);
        *(uint4*)dst = o;
        o.x = pack2(a[8], a[9]);   o.y = pack2(a[10], a[11]);
        o.z = pack2(a[12], a[13]); o.w = pack2(a[14], a[15]);
        *(uint4*)(dst + 8) = o;
    }
    __syncthreads();

    f32x4 acc[2][2];
    {
        bf16x8 wf[8][2];
        load_wfrag<8>(A.wfrag + 56*256, wf, tid);
        zero_acc<2>(acc);
        mfma_compute<2, 8, LDA>(xlds, wf, acc, l16, quad);
    }
    __syncthreads();                                       // A-reads done before overwrite

    // epilogue 1: peff = relu(acc + b + prev); write global (unless LAST) + LDS cols[0,128)
    #pragma unroll
    for (int mt = 0; mt < 2; ++mt)
      #pragma unroll
      for (int nt = 0; nt < 2; ++nt) {
        int col = wave*32 + nt*16 + l16;
        float bv = A.pp_b[col];
        #pragma unroll
        for (int rg = 0; rg < 4; ++rg) {
            int rloc = mt*16 + quad*4 + rg;
            long r = row0 + rloc;
            float prev = STEP1 ? 0.f : A.peff32[r*128 + col];
            float v = fmaxf(acc[mt][nt][rg] + bv + prev, 0.f);
            if (!LAST) A.peff32[r*128 + col] = v;
            xlds[rloc*LDA + col] = (u16)f2bf(v);
        }
      }
    __syncthreads();

    if (MAKEUV) {   // epilogue 2a: UV_out = peff @ [rp_w1 | rp_w2]
        #pragma unroll
        for (int half = 0; half < 2; ++half) {
            bf16x8 wf[4][2];
            load_wfrag<4>(half ? (A.wfrag + 48*256) : (A.wfrag + 40*256), wf, tid);
            zero_acc<2>(acc);
            mfma_compute<2, 4, LDA>(xlds, wf, acc, l16, quad);
            #pragma unroll
            for (int mt = 0; mt < 2; ++mt)
              #pragma unroll
              for (int nt = 0; nt < 2; ++nt) {
                int col = half*128 + wave*32 + nt*16 + l16;
                #pragma unroll
                for (int rg = 0; rg < 4; ++rg) {
                    long r = row0 + mt*16 + quad*4 + rg;
                    UV_out[r*256 + col] = (u16)f2bf(acc[mt][nt][rg]);
                }
              }
        }
    }
    if (LAST) {     // epilogue 2b: fused predictor
        bf16x8 wf[4][2];
        load_wfrag<4>(A.wfrag + 72*256, wf, tid);
        zero_acc<2>(acc);
        mfma_compute<2, 4, LDA>(xlds, wf, acc, l16, quad);
        store_c_lds<2, LDA>(xlds, acc, A.pr_b0, wave, quad, l16, 128);  // h -> [128,256)
        __syncthreads();
        if (tid < 96) {                                    // 32 rows x 3 cols
            int row = tid / 3, col = tid - row * 3;
            float s = A.pr_b1[col];
            const u16* hr = xlds + row * LDA + 128;
            #pragma unroll 8
            for (int k = 0; k < 128; ++k) s += bf2f(hr[k]) * A.pr_w1[k*3 + col];
            A.out[(row0 + row)*3 + col] = s;
        }
    }
}

// ---------------- the single fused kernel (plain launch + manual grid barrier) ----------------
// grid = 256 blocks x 256 threads, all co-resident (capacity >= 2 blocks/CU)
// phase 0: Rr/Rs one-hot scan (64KB chunks, 16-deep ILP) + weight-prep + particle enc
// phase 1: CSR build (blocks 0..7) || relation encoder (blocks 8..255, 1024 tiles)
// phases 2-4: the three propagation steps
__global__ __launch_bounds__(256) void k_all(CoopArgs A) {
    __shared__ __align__(16) u16 xlds[64 * 136];
    __shared__ int cur[NP];
    __shared__ int wsum[4];
    const int tid = threadIdx.x;
    const int bid = blockIdx.x;

    // ---- phase 0 ----
    if (bid < 6) wprep(A, tid, bid);
    else if (bid >= 8 && bid < 136) pe_tile(A, xlds, tid, bid - 8);
    {   // scan: 8192 chunks of 4096 u32x4 (64 KB); pe-blocks get 31, others 33
        int q, st;
        if (bid >= 8 && bid < 136) { q = 31; st = (bid - 8) * 31; }
        else { int idx = (bid < 8) ? bid : (bid - 128); q = 33; st = 3968 + idx * 33; }
        for (int cc = 0; cc < q; ++cc) {
            int chunk = st + cc;
            const u32x4* src; u16* dst; long base;
            if (chunk < 4096) { src = A.Rr4; dst = A.recv; base = (long)chunk * 4096; }
            else              { src = A.Rs4; dst = A.send; base = (long)(chunk - 4096) * 4096; }
            u32x4 v[16];
            #pragma unroll
            for (int k = 0; k < 16; ++k)
                v[k] = __builtin_nontemporal_load(src + base + k*256 + tid);
            #pragma unroll
            for (int k = 0; k < 16; ++k) {
                long i = base + k*256 + tid;
                int c4 = (int)(i & 2047), n = (int)((i >> 11) & 1023), b = (int)(i >> 21);
                int o = b * NR + c4 * 4;
                if (v[k][0]) dst[o + 0] = (u16)n;
                if (v[k][1]) dst[o + 1] = (u16)n;
                if (v[k][2]) dst[o + 2] = (u16)n;
                if (v[k][3]) dst[o + 3] = (u16)n;
            }
        }
    }
    gbar(A.bar + 0, tid);

    // ---- phase 1 ----
    if (bid < 8) csr_build(A, cur, wsum, tid, bid);
    else for (int t = bid - 8; t < 1024; t += 248) enc_tile(A, xlds, tid, t);
    gbar(A.bar + 1, tid);

    // ---- phases 2-4 ----
    pp_step<true,  true,  false>(A, xlds, tid, bid, A.UVa, A.UVa);
    gbar(A.bar + 2, tid);
    pp_step<false, true,  false>(A, xlds, tid, bid, A.UVa, A.UVb);
    gbar(A.bar + 3, tid);
    pp_step<false, false, true >(A, xlds, tid, bid, A.UVb, A.UVa);
}

extern "C" void kernel_launch(void* const* d_in, const int* in_sizes, int n_in,
                              void* d_out, int out_size, void* d_ws, size_t ws_size,
                              hipStream_t stream) {
    // workspace layout (ws_size = 1 GB; peak use ~31 MB)
    char* p = (char*)d_ws;
    u16*    bufP    = (u16*)p;    p += (size_t)NB*NR*128*2;      // 16 MB  P (unsorted)
    u16*    UVa     = (u16*)p;    p += (size_t)NB*NP*256*2;      // 4 MB
    u16*    UVb     = (u16*)p;    p += (size_t)NB*NP*256*2;      // 4 MB
    float*  peff32  = (float*)p;  p += (size_t)NB*NP*128*4;      // 4 MB
    u16*    penc    = (u16*)p;    p += (size_t)NB*NP*128*2;      // 2 MB
    bf16x8* wfrag   = (bf16x8*)p; p += (size_t)80*256*16;        // 320 KB
    int*    row_ptr = (int*)p;    p += (size_t)NB*(NP+1)*4 + 12; // ~32 KB (+pad)
    u16*    recv    = (u16*)p;    p += (size_t)NB*NR*2;          // 128 KB
    u16*    send    = (u16*)p;    p += (size_t)NB*NR*2;          // 128 KB
    unsigned int* pidx = (unsigned int*)p; p += (size_t)NB*NR*4; // 256 KB packed perm|send
    int*    bar     = (int*)p;    p += 64;                       // 4 barrier counters

    CoopArgs ka;
    ka.Rr4   = (const u32x4*)d_in[1];
    ka.Rs4   = (const u32x4*)d_in[2];
    ka.recv  = recv;  ka.send = send;
    ka.state = (const float*)d_in[0];
    ka.Ra    = (const float*)d_in[3];
    ka.re_w0 = (const float*)d_in[9];
    ka.re_w1 = (const float*)d_in[11];
    ka.re_w2 = (const float*)d_in[13];
    ka.rp_w  = (const float*)d_in[15];
    ka.pp_w  = (const float*)d_in[17];
    ka.pr_w0 = (const float*)d_in[19];
    ka.pe_w0 = (const float*)d_in[5];
    ka.pe_w1 = (const float*)d_in[7];
    ka.wfrag = wfrag;
    ka.pe_b0 = (const float*)d_in[6];
    ka.pe_b1 = (const float*)d_in[8];
    ka.re_b0 = (const float*)d_in[10];
    ka.re_b1 = (const float*)d_in[12];
    ka.re_b2 = (const float*)d_in[14];
    ka.rp_b  = (const float*)d_in[16];
    ka.pp_b  = (const float*)d_in[18];
    ka.pr_b0 = (const float*)d_in[20];
    ka.pr_w1 = (const float*)d_in[21];
    ka.pr_b1 = (const float*)d_in[22];
    ka.penc  = penc;  ka.bufP = bufP;
    ka.UVa   = UVa;   ka.UVb  = UVb;
    ka.peff32 = peff32;
    ka.out   = (float*)d_out;
    ka.row_ptr = row_ptr;
    ka.pidx  = pidx;
    ka.bar   = bar;

    hipMemsetAsync(bar, 0, 64, stream);        // one-shot barrier counters -> 0
    k_all<<<256, 256, 0, stream>>>(ka);
}

// Round 6
// 602.719 us; speedup vs baseline: 1.2393x; 1.2393x over previous
//
#include <hip/hip_runtime.h>

#define NB 8
#define NP 1024
#define NR 8192

typedef unsigned short u16;
typedef __attribute__((ext_vector_type(8))) short bf16x8;   // 8 bf16 (4 VGPRs)
typedef __attribute__((ext_vector_type(4))) float f32x4;
typedef __attribute__((ext_vector_type(4))) unsigned int u32x4;

#define MFMA __builtin_amdgcn_mfma_f32_16x16x32_bf16

static __device__ __forceinline__ float bf2f(u16 u) {
    union { unsigned int i; float f; } v; v.i = ((unsigned int)u) << 16; return v.f;
}
static __device__ __forceinline__ unsigned int f2bf(float f) {
    union { float fv; unsigned int i; } v; v.fv = f;
    unsigned int r = v.i + 0x7FFFu + ((v.i >> 16) & 1u);   // RNE
    return r >> 16;
}
static __device__ __forceinline__ unsigned int pack2(float a, float b) {
    return f2bf(a) | (f2bf(b) << 16);
}
static __device__ __forceinline__ void unpk8(uint4 v, float* o) {
    o[0] = bf2f((u16)(v.x & 0xFFFF)); o[1] = bf2f((u16)(v.x >> 16));
    o[2] = bf2f((u16)(v.y & 0xFFFF)); o[3] = bf2f((u16)(v.y >> 16));
    o[4] = bf2f((u16)(v.z & 0xFFFF)); o[5] = bf2f((u16)(v.z >> 16));
    o[6] = bf2f((u16)(v.w & 0xFFFF)); o[7] = bf2f((u16)(v.w >> 16));
}

// ---------------- MFMA tile core (MT*16 rows x 128 cols per block) ----------------
template<int KC>
static __device__ __forceinline__ void load_wfrag(
    const bf16x8* __restrict__ fb, bf16x8 (&wf)[KC][2], int tid)
{
    #pragma unroll
    for (int kc = 0; kc < KC; ++kc)
      #pragma unroll
      for (int nt = 0; nt < 2; ++nt)
        wf[kc][nt] = fb[(kc*2 + nt)*256 + tid];
}

template<int MT, int KC, int LDA>
static __device__ __forceinline__ void mfma_compute(
    const u16* xlds, const bf16x8 (&wf)[KC][2], f32x4 (&acc)[MT][2],
    int l16, int quad)
{
    #pragma unroll
    for (int kc = 0; kc < KC; ++kc) {
        bf16x8 a[MT];
        #pragma unroll
        for (int mt = 0; mt < MT; ++mt)
            a[mt] = *(const bf16x8*)(xlds + (mt*16 + l16)*LDA + kc*32 + quad*8);
        #pragma unroll
        for (int mt = 0; mt < MT; ++mt) {
            acc[mt][0] = MFMA(a[mt], wf[kc][0], acc[mt][0], 0, 0, 0);
            acc[mt][1] = MFMA(a[mt], wf[kc][1], acc[mt][1], 0, 0, 0);
        }
    }
}

template<int MT>
static __device__ __forceinline__ void zero_acc(f32x4 (&acc)[MT][2]) {
    #pragma unroll
    for (int mt = 0; mt < MT; ++mt)
      #pragma unroll
      for (int nt = 0; nt < 2; ++nt)
        acc[mt][nt] = f32x4{0.f, 0.f, 0.f, 0.f};
}

template<int MT, int LDA>
static __device__ __forceinline__ void store_c_lds(
    u16* xlds, const f32x4 (&acc)[MT][2], const float* __restrict__ bias,
    int wave, int quad, int l16, int coloff = 0)
{
    #pragma unroll
    for (int mt = 0; mt < MT; ++mt)
      #pragma unroll
      for (int nt = 0; nt < 2; ++nt) {
        int col = wave*32 + nt*16 + l16;
        float bv = bias[col];
        #pragma unroll
        for (int rg = 0; rg < 4; ++rg)
            xlds[(mt*16 + quad*4 + rg)*LDA + coloff + col] =
                (u16)f2bf(fmaxf(acc[mt][nt][rg] + bv, 0.f));
      }
}

template<int MT, bool RELU>
static __device__ __forceinline__ void store_c_glob(
    u16* __restrict__ out, long row0, const f32x4 (&acc)[MT][2],
    const float* __restrict__ bias, int wave, int quad, int l16)
{
    #pragma unroll
    for (int mt = 0; mt < MT; ++mt)
      #pragma unroll
      for (int nt = 0; nt < 2; ++nt) {
        int col = wave*32 + nt*16 + l16;
        float bv = bias[col];
        #pragma unroll
        for (int rg = 0; rg < 4; ++rg) {
            long r = row0 + mt*16 + quad*4 + rg;
            float v = acc[mt][nt][rg] + bv;
            if (RELU) v = fmaxf(v, 0.f);
            out[r*128 + col] = (u16)f2bf(v);
        }
      }
}

// ------- fused: blocks 0..7 weight prep; blocks 8..135 particle encoder (self-
// built frags, independent of scan); blocks 136.. one-hot index scan -------
__global__ __launch_bounds__(256) void k_idxprep(
    const u32x4* __restrict__ Rr4, const u32x4* __restrict__ Rs4,
    u16* __restrict__ recv, u16* __restrict__ send,
    const float* __restrict__ w0, const float* __restrict__ w1,
    const float* __restrict__ w2, const float* __restrict__ w3,
    const float* __restrict__ w4, const float* __restrict__ w5,
    const float* __restrict__ w6, const float* __restrict__ w7,
    bf16x8* __restrict__ wfrag,
    const float* __restrict__ state, const float* __restrict__ pe_b0,
    const float* __restrict__ pe_b1, u16* __restrict__ penc)
{
    constexpr int LDA = 136;
    __shared__ __align__(16) u16 xlds[64 * LDA];
    int tid = threadIdx.x;
    const int wave = tid >> 6, quad = (tid >> 4) & 3, l16 = tid & 15;

    if (blockIdx.x < 8) {                     // ---- weight prep path ----
        const float* W; int KC, kv, off;
        switch (blockIdx.x) {
            case 0:  W = w0; KC = 3;  kv = 65;  off = 0;  break;   // re_w0 (pad 65->96)
            case 1:  W = w1; KC = 4;  kv = 128; off = 6;  break;   // re_w1
            case 2:  W = w2; KC = 4;  kv = 128; off = 14; break;   // re_w2
            case 3:  W = w3; KC = 1;  kv = 32;  off = 22; break;   // pe_w0
            case 4:  W = w4; KC = 4;  kv = 128; off = 24; break;   // pe_w1
            case 5:  W = w5; KC = 12; kv = 384; off = 32; break;   // rp_w
            case 6:  W = w6; KC = 8;  kv = 256; off = 56; break;   // pp_w
            default: W = w7; KC = 4;  kv = 128; off = 72; break;   // pr_w0
        }
        for (int kc = 0; kc < KC; ++kc)
          for (int nt = 0; nt < 2; ++nt) {
            bf16x8 f;
            #pragma unroll
            for (int j = 0; j < 8; ++j) {
                int k = kc*32 + quad*8 + j;
                f[j] = (k < kv) ? (short)f2bf(W[k*128 + wave*32 + nt*16 + l16]) : (short)0;
            }
            wfrag[(off + kc*2 + nt)*256 + tid] = f;
          }
        return;
    }

    if (blockIdx.x < 136) {                   // ---- particle encoder path ----
        const long row0 = (long)(blockIdx.x - 8) * 64;
        for (int idx = tid; idx < 64 * 8; idx += 256) {    // stage state fp32->bf16
            int r = idx >> 3, c = idx & 7;
            float4 v = *(const float4*)(state + (row0 + r)*32 + c*4);
            uint2 o; o.x = pack2(v.x, v.y); o.y = pack2(v.z, v.w);
            *(uint2*)(xlds + r*LDA + c*4) = o;
        }
        __syncthreads();
        f32x4 acc[4][2];
        zero_acc<4>(acc);
        {   // pe_w0 frags built directly (32x128, KC=1)
            bf16x8 wf[1][2];
            #pragma unroll
            for (int nt = 0; nt < 2; ++nt)
              #pragma unroll
              for (int j = 0; j < 8; ++j) {
                int k = quad*8 + j;
                wf[0][nt][j] = (short)f2bf(w3[k*128 + wave*32 + nt*16 + l16]);
              }
            mfma_compute<4, 1, LDA>(xlds, wf, acc, l16, quad);
        }
        __syncthreads();
        store_c_lds<4, LDA>(xlds, acc, pe_b0, wave, quad, l16);
        __syncthreads();
        zero_acc<4>(acc);
        {   // pe_w1 frags built directly (128x128, KC=4)
            bf16x8 wf[4][2];
            #pragma unroll
            for (int kc = 0; kc < 4; ++kc)
              #pragma unroll
              for (int nt = 0; nt < 2; ++nt)
                #pragma unroll
                for (int j = 0; j < 8; ++j) {
                    int k = kc*32 + quad*8 + j;
                    wf[kc][nt][j] = (short)f2bf(w4[k*128 + wave*32 + nt*16 + l16]);
                }
            mfma_compute<4, 4, LDA>(xlds, wf, acc, l16, quad);
        }
        store_c_glob<4, true>(penc, row0, acc, pe_b1, wave, quad, l16);
        return;
    }

    // ---- index scan path: 8 chunks/thread (32 KB/block), NT loads ----
    int sid = blockIdx.x - 136;
    int mat = sid & 1;
    const u32x4* src = mat ? Rs4 : Rr4;
    u16* dst = mat ? send : recv;
    long base = (long)(sid >> 1) * 2048 + tid;
    u32x4 v[8];
    #pragma unroll
    for (int k = 0; k < 8; ++k)
        v[k] = __builtin_nontemporal_load(src + base + k*256);
    #pragma unroll
    for (int k = 0; k < 8; ++k) {
        long i = base + k*256;
        int c4 = (int)(i & 2047), n = (int)((i >> 11) & 1023), b = (int)(i >> 21);
        int o = b * NR + c4 * 4;
        if (v[k][0]) dst[o + 0] = (u16)n;
        if (v[k][1]) dst[o + 1] = (u16)n;
        if (v[k][2]) dst[o + 2] = (u16)n;
        if (v[k][3]) dst[o + 3] = (u16)n;
    }
}

// ------- fused: blocks 0..7 = CSR build (row_ptr + packed perm/send pidx);
//         blocks 8..1031 = relation encoder writing bufP UNSORTED (bufP[rel]).
//         No cross-dependency -> csr runs hidden under encrel. -------
__global__ __launch_bounds__(256) void k_csrenc(
    const float* __restrict__ state, const float* __restrict__ Ra,
    const u16* __restrict__ recv, const u16* __restrict__ send,
    int* __restrict__ row_ptr, unsigned int* __restrict__ pidx,
    const bf16x8* __restrict__ f_re0, const float* __restrict__ re_b0,
    const bf16x8* __restrict__ f_re1, const float* __restrict__ re_b1,
    const bf16x8* __restrict__ f_re2, const float* __restrict__ re_b2,
    const bf16x8* __restrict__ f_rpP, const float* __restrict__ rp_b,
    u16* __restrict__ bufP)
{
    constexpr int LDA = 136;                   // 128 + 8 (also holds 96-col input)
    __shared__ __align__(16) u16 xlds[64 * LDA];
    __shared__ int cur[NP];
    __shared__ int wsum[4];
    const int tid = threadIdx.x;

    if (blockIdx.x < 8) {                      // ---- CSR path (256 threads) ----
        const int b = blockIdx.x;
        for (int i = tid; i < NP; i += 256) cur[i] = 0;
        __syncthreads();
        int pv[32];
        #pragma unroll
        for (int k = 0; k < 32; ++k) {
            pv[k] = recv[b * NR + k * 256 + tid] & 1023;
            atomicAdd(&cur[pv[k]], 1);
        }
        __syncthreads();
        int4 c4v = ((const int4*)cur)[tid];    // bins 4t..4t+3
        int s = c4v.x + c4v.y + c4v.z + c4v.w;
        int si = s;                            // inclusive wave scan over thread sums
        #pragma unroll
        for (int off = 1; off < 64; off <<= 1) {
            int u = __shfl_up(si, off);
            if ((tid & 63) >= off) si += u;
        }
        if ((tid & 63) == 63) wsum[tid >> 6] = si;
        __syncthreads();
        if (tid == 0) {
            int a0 = 0;
            #pragma unroll
            for (int i = 0; i < 4; ++i) { int w = wsum[i]; wsum[i] = a0; a0 += w; }
        }
        __syncthreads();
        int base = si - s + wsum[tid >> 6];    // exclusive prefix of thread chunk
        int e0 = base, e1 = base + c4v.x, e2 = e1 + c4v.y, e3 = e2 + c4v.z;
        int* rp = row_ptr + b * (NP + 1);
        rp[tid*4 + 0] = e0; rp[tid*4 + 1] = e1;
        rp[tid*4 + 2] = e2; rp[tid*4 + 3] = e3;
        cur[tid*4 + 0] = e0; cur[tid*4 + 1] = e1;
        cur[tid*4 + 2] = e2; cur[tid*4 + 3] = e3;
        if (tid == 255) rp[NP] = e3 + c4v.w;
        __syncthreads();
        #pragma unroll
        for (int k = 0; k < 32; ++k) {
            int r = k * 256 + tid;
            int j = atomicAdd(&cur[pv[k]], 1) & 8191;
            pidx[b * NR + j] = (unsigned int)(r & 8191)
                             | ((unsigned int)(send[b * NR + r] & 1023) << 16);
        }
        return;
    }

    // ---- relation encoder path ----
    const int wave = tid >> 6, quad = (tid >> 4) & 3, l16 = tid & 15;
    f32x4 acc[4][2];
    const int row0 = (blockIdx.x - 8) * 64;
    const int b = row0 >> 13;
    {   // stage gathered input: [state_recv(32) | state_send(32) | Ra(1) | zeros->96]
        int r = tid >> 2, tt = tid & 3;
        int rel = row0 + r;
        u16* dst = xlds + r * LDA;
        int ri = recv[rel] & 1023;
        int si = send[rel] & 1023;
        const float* rrow = state + ((long)(b*NP + ri)) * 32;
        const float* srow = state + ((long)(b*NP + si)) * 32;
        float4 a0 = *(const float4*)(rrow + tt*8);
        float4 a1 = *(const float4*)(rrow + tt*8 + 4);
        uint4 o;
        o.x = pack2(a0.x, a0.y); o.y = pack2(a0.z, a0.w);
        o.z = pack2(a1.x, a1.y); o.w = pack2(a1.z, a1.w);
        *(uint4*)(dst + tt*8) = o;
        float4 s0 = *(const float4*)(srow + tt*8);
        float4 s1 = *(const float4*)(srow + tt*8 + 4);
        o.x = pack2(s0.x, s0.y); o.y = pack2(s0.z, s0.w);
        o.z = pack2(s1.x, s1.y); o.w = pack2(s1.z, s1.w);
        *(uint4*)(dst + 32 + tt*8) = o;
        if (tt == 3) {
            uint4 z = make_uint4(0, 0, 0, 0);
            *(uint4*)(dst + 64) = z; *(uint4*)(dst + 72) = z;
            *(uint4*)(dst + 80) = z; *(uint4*)(dst + 88) = z;
            dst[64] = (u16)f2bf(Ra[rel]);
        }
    }
    __syncthreads();
    zero_acc<4>(acc);
    {
        bf16x8 wf[3][2];
        load_wfrag<3>(f_re0, wf, tid);
        mfma_compute<4, 3, LDA>(xlds, wf, acc, l16, quad);
    }
    __syncthreads();
    store_c_lds<4, LDA>(xlds, acc, re_b0, wave, quad, l16);
    __syncthreads();
    zero_acc<4>(acc);
    {
        bf16x8 wf[4][2];
        load_wfrag<4>(f_re1, wf, tid);
        mfma_compute<4, 4, LDA>(xlds, wf, acc, l16, quad);
    }
    __syncthreads();
    store_c_lds<4, LDA>(xlds, acc, re_b1, wave, quad, l16);
    __syncthreads();
    zero_acc<4>(acc);
    {
        bf16x8 wf[4][2];
        load_wfrag<4>(f_re2, wf, tid);
        mfma_compute<4, 4, LDA>(xlds, wf, acc, l16, quad);
    }
    __syncthreads();
    store_c_lds<4, LDA>(xlds, acc, re_b2, wave, quad, l16);   // relation_encode
    __syncthreads();
    zero_acc<4>(acc);
    {
        bf16x8 wf[4][2];
        load_wfrag<4>(f_rpP, wf, tid);
        mfma_compute<4, 4, LDA>(xlds, wf, acc, l16, quad);
    }
    // P (pre-relu) stored UNSORTED at bufP[rel] -> contiguous coalesced stores
    #pragma unroll
    for (int mt = 0; mt < 4; ++mt)
      #pragma unroll
      for (int nt = 0; nt < 2; ++nt) {
        int col = wave*32 + nt*16 + l16;
        float bv = rp_b[col];
        #pragma unroll
        for (int rg = 0; rg < 4; ++rg) {
            int rl = mt*16 + quad*4 + rg;
            bufP[((long)(row0 + rl))*128 + col] = (u16)f2bf(acc[mt][nt][rg] + bv);
        }
      }
}

// ------- particle propagator (16 rows/block, 512 blocks -> 2+ blocks/CU for
//   latency hiding of the gather loop; was 256 blocks = 1/CU = 4 waves):
//   agg = sum over CSR range [s0,e0) of relu(P[perm[j]] + U[p] + V[send[perm[j]]]);
//   batch-4: issue all row-loads before consuming. 16 threads/particle, 8 cols each.
template<bool STEP1, bool MAKEUV, bool LAST>
__global__ __launch_bounds__(256) void k_pp(
    const u16* __restrict__ penc, const u16* __restrict__ bufP,
    const u16* __restrict__ UV_in, u16* __restrict__ UV_out,
    const int* __restrict__ row_ptr, const unsigned int* __restrict__ pidx,
    const bf16x8* __restrict__ f_pp, const float* __restrict__ pp_b,
    const bf16x8* __restrict__ f_U, const bf16x8* __restrict__ f_V,
    const bf16x8* __restrict__ f_pr0, const float* __restrict__ pr_b0,
    const float* __restrict__ pr_w1, const float* __restrict__ pr_b1,
    float* __restrict__ peff32_io, float* __restrict__ out)
{
    constexpr int LDA = 264;                   // 256 + 8
    __shared__ __align__(16) u16 xlds[16 * LDA];
    const int tid = threadIdx.x;
    const int wave = tid >> 6, quad = (tid >> 4) & 3, l16 = tid & 15;
    const long row0 = (long)blockIdx.x * 16;

    {   // seg0: particle_encode (bf16), 16 rows x 128 cols, one uint4/thread
        int r = tid >> 4, c = tid & 15;
        *(uint4*)(xlds + r*LDA + c*8) = *(const uint4*)(penc + (row0 + r)*128 + c*8);
    }
    {   // seg1: agg; 16 threads/particle, 8 cols each
        int pp = tid >> 4;
        int cq = tid & 15;
        int gp = (int)row0 + pp;
        int b = gp >> 10, pl = gp & 1023;
        const int* rp = row_ptr + b * (NP + 1);
        int s0 = rp[pl], e0 = rp[pl + 1];
        const unsigned int* pidxb = pidx + b * NR;
        const u16* bufPb = bufP + (long)b * NR * 128;
        float a[8];
        #pragma unroll
        for (int t = 0; t < 8; ++t) a[t] = 0.f;
        float uv[8];
        if (!STEP1) {
            const u16* ur = UV_in + ((long)gp)*256 + cq*8;
            unpk8(*(const uint4*)ur, uv);
        }
        const u16* uvb = UV_in + ((long)(b*NP))*256 + 128 + cq*8;
        for (int jb = s0; jb < e0; jb += 4) {
            int m = e0 - jb; if (m > 4) m = 4;
            unsigned int ids[4];
            #pragma unroll
            for (int t = 0; t < 4; ++t) {
                int j = jb + t; if (j > e0 - 1) j = e0 - 1;   // clamp (loads stay valid)
                ids[t] = pidxb[j];
            }
            uint4 P0[4], V0[4];
            #pragma unroll
            for (int t = 0; t < 4; ++t) {
                P0[t] = *(const uint4*)(bufPb + ((long)(ids[t] & 8191u))*128 + cq*8);
                if (!STEP1)
                    V0[t] = *(const uint4*)(uvb + (long)((ids[t] >> 16) & 1023u)*256);
            }
            #pragma unroll
            for (int t = 0; t < 4; ++t) {
                if (t < m) {
                    float pv[8];
                    unpk8(P0[t], pv);
                    if (STEP1) {
                        #pragma unroll
                        for (int e = 0; e < 8; ++e) a[e] += fmaxf(pv[e], 0.f);
                    } else {
                        float vv[8];
                        unpk8(V0[t], vv);
                        #pragma unroll
                        for (int e = 0; e < 8; ++e)
                            a[e] += fmaxf(pv[e] + uv[e] + vv[e], 0.f);
                    }
                }
            }
        }
        u16* dst = xlds + pp*LDA + 128 + cq*8;
        uint4 o;
        o.x = pack2(a[0], a[1]); o.y = pack2(a[2], a[3]);
        o.z = pack2(a[4], a[5]); o.w = pack2(a[6], a[7]);
        *(uint4*)dst = o;
    }
    __syncthreads();

    f32x4 acc[1][2];
    {
        bf16x8 wf[8][2];
        load_wfrag<8>(f_pp, wf, tid);
        zero_acc<1>(acc);
        mfma_compute<1, 8, LDA>(xlds, wf, acc, l16, quad);
    }
    __syncthreads();                                       // A-reads done before overwrite

    // epilogue 1: peff = relu(acc + b + prev); write global (unless LAST) + LDS cols[0,128)
    #pragma unroll
    for (int nt = 0; nt < 2; ++nt) {
        int col = wave*32 + nt*16 + l16;
        float bv = pp_b[col];
        #pragma unroll
        for (int rg = 0; rg < 4; ++rg) {
            int rloc = quad*4 + rg;
            long r = row0 + rloc;
            float prev = STEP1 ? 0.f : peff32_io[r*128 + col];
            float v = fmaxf(acc[0][nt][rg] + bv + prev, 0.f);
            if (!LAST) peff32_io[r*128 + col] = v;
            xlds[rloc*LDA + col] = (u16)f2bf(v);
        }
    }
    __syncthreads();

    if (MAKEUV) {   // epilogue 2a: UV_out = peff @ [rp_w1 | rp_w2]
        #pragma unroll
        for (int half = 0; half < 2; ++half) {
            bf16x8 wf[4][2];
            load_wfrag<4>(half ? f_V : f_U, wf, tid);
            zero_acc<1>(acc);
            mfma_compute<1, 4, LDA>(xlds, wf, acc, l16, quad);
            #pragma unroll
            for (int nt = 0; nt < 2; ++nt) {
                int col = half*128 + wave*32 + nt*16 + l16;
                #pragma unroll
                for (int rg = 0; rg < 4; ++rg) {
                    long r = row0 + quad*4 + rg;
                    UV_out[r*256 + col] = (u16)f2bf(acc[0][nt][rg]);
                }
            }
        }
    }
    if (LAST) {     // epilogue 2b: fused predictor
        bf16x8 wf[4][2];
        load_wfrag<4>(f_pr0, wf, tid);
        zero_acc<1>(acc);
        mfma_compute<1, 4, LDA>(xlds, wf, acc, l16, quad);
        store_c_lds<1, LDA>(xlds, acc, pr_b0, wave, quad, l16, 128);  // h -> cols [128,256)
        __syncthreads();
        if (tid < 48) {                                    // 16 rows x 3 cols
            int row = tid / 3, col = tid - row * 3;
            float s = pr_b1[col];
            const u16* hr = xlds + row * LDA + 128;
            #pragma unroll 8
            for (int k = 0; k < 128; ++k) s += bf2f(hr[k]) * pr_w1[k*3 + col];
            out[(row0 + row)*3 + col] = s;
        }
    }
}

extern "C" void kernel_launch(void* const* d_in, const int* in_sizes, int n_in,
                              void* d_out, int out_size, void* d_ws, size_t ws_size,
                              hipStream_t stream) {
    const float* state = (const float*)d_in[0];
    const float* Rr    = (const float*)d_in[1];
    const float* Rs    = (const float*)d_in[2];
    const float* Ra    = (const float*)d_in[3];
    // d_in[4] = pstep (=3, constant)
    const float* pe_w0 = (const float*)d_in[5];
    const float* pe_b0 = (const float*)d_in[6];
    const float* pe_w1 = (const float*)d_in[7];
    const float* pe_b1 = (const float*)d_in[8];
    const float* re_w0 = (const float*)d_in[9];
    const float* re_b0 = (const float*)d_in[10];
    const float* re_w1 = (const float*)d_in[11];
    const float* re_b1 = (const float*)d_in[12];
    const float* re_w2 = (const float*)d_in[13];
    const float* re_b2 = (const float*)d_in[14];
    const float* rp_w  = (const float*)d_in[15];
    const float* rp_b  = (const float*)d_in[16];
    const float* pp_w  = (const float*)d_in[17];
    const float* pp_b  = (const float*)d_in[18];
    const float* pr_w0 = (const float*)d_in[19];
    const float* pr_b0 = (const float*)d_in[20];
    const float* pr_w1 = (const float*)d_in[21];
    const float* pr_b1 = (const float*)d_in[22];

    // workspace layout (ws_size = 1 GB; peak use ~31 MB)
    char* p = (char*)d_ws;
    u16*    bufP    = (u16*)p;    p += (size_t)NB*NR*128*2;      // 16 MB  P (unsorted)
    u16*    UVa     = (u16*)p;    p += (size_t)NB*NP*256*2;      // 4 MB
    u16*    UVb     = (u16*)p;    p += (size_t)NB*NP*256*2;      // 4 MB
    float*  peff32  = (float*)p;  p += (size_t)NB*NP*128*4;      // 4 MB
    u16*    penc    = (u16*)p;    p += (size_t)NB*NP*128*2;      // 2 MB
    bf16x8* wfrag   = (bf16x8*)p; p += (size_t)80*256*16;        // 320 KB
    int*    row_ptr = (int*)p;    p += (size_t)NB*(NP+1)*4 + 12; // ~32 KB (+pad)
    u16*    recv    = (u16*)p;    p += (size_t)NB*NR*2;          // 128 KB
    u16*    send    = (u16*)p;    p += (size_t)NB*NR*2;          // 128 KB
    unsigned int* pidx = (unsigned int*)p; p += (size_t)NB*NR*4; // 256 KB packed perm|send

    // frag-slot offsets
    const bf16x8* f_re0 = wfrag + 0*256;
    const bf16x8* f_re1 = wfrag + 6*256;
    const bf16x8* f_re2 = wfrag + 14*256;
    const bf16x8* f_rpP = wfrag + 32*256;   // rp_w rows [0,128)
    const bf16x8* f_rpU = wfrag + 40*256;   // rp_w rows [128,256)
    const bf16x8* f_rpV = wfrag + 48*256;   // rp_w rows [256,384)
    const bf16x8* f_pp  = wfrag + 56*256;
    const bf16x8* f_pr0 = wfrag + 72*256;

    float* outp = (float*)d_out;

    // 0) fused weight prep + particle encoder + one-hot index scan
    k_idxprep<<<16520, 256, 0, stream>>>((const u32x4*)Rr, (const u32x4*)Rs, recv, send,
                                         re_w0, re_w1, re_w2, pe_w0, pe_w1, rp_w, pp_w, pr_w0,
                                         wfrag, state, pe_b0, pe_b1, penc);
    // 1) CSR build (8 blocks) runs concurrently with relation encoder (1024 blocks)
    k_csrenc<<<1032, 256, 0, stream>>>(state, Ra, recv, send, row_ptr, pidx,
                                       f_re0, re_b0, f_re1, re_b1, f_re2, re_b2,
                                       f_rpP, rp_b, bufP);
    // 2) propagation: step 1 (U=V=0, makes UVa), step 2 (UVa -> UVb), step 3 (UVb -> pred)
    k_pp<true,  true,  false><<<512, 256, 0, stream>>>(
        penc, bufP, UVa, UVa, row_ptr, pidx, f_pp, pp_b,
        f_rpU, f_rpV, f_pr0, pr_b0, pr_w1, pr_b1, peff32, outp);
    k_pp<false, true,  false><<<512, 256, 0, stream>>>(
        penc, bufP, UVa, UVb, row_ptr, pidx, f_pp, pp_b,
        f_rpU, f_rpV, f_pr0, pr_b0, pr_w1, pr_b1, peff32, outp);
    k_pp<false, false, true><<<512, 256, 0, stream>>>(
        penc, bufP, UVb, UVa, row_ptr, pidx, f_pp, pp_b,
        f_rpU, f_rpV, f_pr0, pr_b0, pr_w1, pr_b1, peff32, outp);
}